// Round 10
// baseline (294.825 us; speedup 1.0000x reference)
//
#include <hip/hip_runtime.h>
#include <hip/hip_bf16.h>
#include <math.h>

#define BB 64
#define HH 1024
#define SS 2048
#define VV 50257

typedef float f32x4 __attribute__((ext_vector_type(4)));
typedef short bf16x8 __attribute__((ext_vector_type(8)));

__device__ __forceinline__ float sigf(float x){ return 1.0f/(1.0f+__expf(-x)); }
__device__ __forceinline__ short f2bf(float f){
  __hip_bfloat16 h = __float2bfloat16(f);
  return __builtin_bit_cast(short, h);
}
__device__ __forceinline__ float bf2f(short s){
  __hip_bfloat16 h = __builtin_bit_cast(__hip_bfloat16, s);
  return __bfloat162float(h);
}

// ------ prep: A = [emb[seq] | h0] split into bf16 hi/lo pair  [64][2048] -----
__global__ void k_prep(const int* __restrict__ seq, const float* __restrict__ embW,
                       const float* __restrict__ h0,
                       short* __restrict__ Ahi, short* __restrict__ Alo){
  const int b = blockIdx.x;
  const int k = threadIdx.x * 8;     // 0..2047
  const float* src = (k < 1024) ? (embW + (size_t)seq[b]*1024 + k)
                                : (h0 + (size_t)b*1024 + (k - 1024));
  float4 v0 = *(const float4*)src;
  float4 v1 = *(const float4*)(src + 4);
  float v[8] = {v0.x,v0.y,v0.z,v0.w,v1.x,v1.y,v1.z,v1.w};
  bf16x8 hi, lo;
  #pragma unroll
  for (int j = 0; j < 8; ++j) {
    short h = f2bf(v[j]);
    hi[j] = h;
    lo[j] = f2bf(v[j] - bf2f(h));
  }
  *(bf16x8*)(Ahi + (size_t)b*2048 + k) = hi;
  *(bf16x8*)(Alo + (size_t)b*2048 + k) = lo;
}

// ------ gates GEMM via bf16-pair MFMA: partials dst[sk][64][4096] ------------
__global__ __launch_bounds__(256, 3)
void k_gates(const short* __restrict__ Ahi, const short* __restrict__ Alo,
             const float* __restrict__ W_ih, const float* __restrict__ W_hh,
             float* __restrict__ dst)
{
  const int tid = threadIdx.x;
  const int wave = tid >> 6, lane = tid & 63;
  const int r = lane & 15, g = lane >> 4;
  const int nb = blockIdx.x, sk = blockIdx.y;
  const int n0 = nb*128 + wave*32;
  const int kbase = sk*128;
  const float* Wm = (kbase < 1024) ? W_ih : W_hh;
  const int kw = (kbase < 1024) ? kbase : (kbase - 1024);

  f32x4 acc[4][2] = {};

  #pragma unroll
  for (int ks = 0; ks < 4; ++ks) {
    const int kk = kbase + ks*32 + g*8;     // A offset
    const int ko = kw   + ks*32 + g*8;      // W offset
    bf16x8 ahi[4], alo[4];
    #pragma unroll
    for (int mf = 0; mf < 4; ++mf) {
      ahi[mf] = *(const bf16x8*)(Ahi + (size_t)(mf*16 + r)*2048 + kk);
      alo[mf] = *(const bf16x8*)(Alo + (size_t)(mf*16 + r)*2048 + kk);
    }
    #pragma unroll
    for (int nf = 0; nf < 2; ++nf) {
      const int n = n0 + nf*16 + r;
      const float* wp = Wm + (size_t)n*1024 + ko;
      float4 w0 = *(const float4*)wp;
      float4 w1 = *(const float4*)(wp + 4);
      float wv[8] = {w0.x,w0.y,w0.z,w0.w,w1.x,w1.y,w1.z,w1.w};
      bf16x8 whi, wlo;
      #pragma unroll
      for (int j = 0; j < 8; ++j) {
        short h = f2bf(wv[j]);
        whi[j] = h;
        wlo[j] = f2bf(wv[j] - bf2f(h));
      }
      #pragma unroll
      for (int mf = 0; mf < 4; ++mf) {
        acc[mf][nf] = __builtin_amdgcn_mfma_f32_16x16x32_bf16(ahi[mf], whi, acc[mf][nf], 0,0,0);
        acc[mf][nf] = __builtin_amdgcn_mfma_f32_16x16x32_bf16(alo[mf], whi, acc[mf][nf], 0,0,0);
        acc[mf][nf] = __builtin_amdgcn_mfma_f32_16x16x32_bf16(ahi[mf], wlo, acc[mf][nf], 0,0,0);
      }
    }
  }

  #pragma unroll
  for (int nf = 0; nf < 2; ++nf) {
    const int n = n0 + nf*16 + r;
    #pragma unroll
    for (int mf = 0; mf < 4; ++mf)
      #pragma unroll
      for (int j = 0; j < 4; ++j)
        dst[((size_t)sk*64 + (mf*16 + g*4 + j))*4096 + n] = acc[mf][nf][j];
  }
}

// -------- fused split-K reduce + bias + LSTM pointwise -> h, c, concA[:, :1024]
__global__ void k_rlstm(const float* __restrict__ part, const float* __restrict__ b_ih,
                        const float* __restrict__ b_hh, const float* __restrict__ c0,
                        float* __restrict__ h_out, float* __restrict__ c_out,
                        short* __restrict__ concA, int SK){
  int idx = blockIdx.x*256 + threadIdx.x;    // 64*1024
  int b = idx >> 10, k = idx & 1023;
  float gi = b_ih[k]      + b_hh[k];
  float gf = b_ih[1024+k] + b_hh[1024+k];
  float gg = b_ih[2048+k] + b_hh[2048+k];
  float go = b_ih[3072+k] + b_hh[3072+k];
  const float* p = part + (size_t)b*4096 + k;
  for (int s = 0; s < SK; ++s) {
    const float* ps = p + (size_t)s*64*4096;
    gi += ps[0]; gf += ps[1024]; gg += ps[2048]; go += ps[3072];
  }
  float c = sigf(gf)*c0[idx] + sigf(gi)*tanhf(gg);
  float h = sigf(go)*tanhf(c);
  c_out[idx] = c;
  h_out[idx] = h;
  concA[(size_t)b*2048 + k] = f2bf(h);
}

// ---------------- streaming bf16 MFMA GEMM (concat): partials dst[sk][64][N] --
__global__ __launch_bounds__(256)
void k_mfma(const short* __restrict__ A, int lda,
            const float* __restrict__ W1, int ldw,
            float* __restrict__ dst, int N, int Ktot)
{
  const int tid  = threadIdx.x;
  const int wave = tid >> 6, lane = tid & 63;
  const int nb = blockIdx.x, sk = blockIdx.y, SK = gridDim.y;
  const int ksteps = Ktot >> 5;
  const int kps = ksteps / SK;
  const int k0 = sk * kps;
  const int n0 = nb*128 + wave*32;
  const int r = lane & 15, g = lane >> 4;

  f32x4 acc[4][2] = {};

  for (int ks = k0; ks < k0 + kps; ++ks) {
    const int kk = (ks << 5) + g*8;
    bf16x8 af[4];
    #pragma unroll
    for (int mf = 0; mf < 4; ++mf)
      af[mf] = *(const bf16x8*)(A + (size_t)(mf*16 + r)*lda + kk);
    #pragma unroll
    for (int nf = 0; nf < 2; ++nf) {
      const int n = n0 + nf*16 + r;
      const float* wp = W1 + (size_t)n*ldw + kk;
      float4 w0 = *(const float4*)wp;
      float4 w1 = *(const float4*)(wp + 4);
      bf16x8 bfr;
      bfr[0]=f2bf(w0.x); bfr[1]=f2bf(w0.y); bfr[2]=f2bf(w0.z); bfr[3]=f2bf(w0.w);
      bfr[4]=f2bf(w1.x); bfr[5]=f2bf(w1.y); bfr[6]=f2bf(w1.z); bfr[7]=f2bf(w1.w);
      #pragma unroll
      for (int mf = 0; mf < 4; ++mf)
        acc[mf][nf] = __builtin_amdgcn_mfma_f32_16x16x32_bf16(af[mf], bfr, acc[mf][nf], 0, 0, 0);
    }
  }

  #pragma unroll
  for (int nf = 0; nf < 2; ++nf) {
    const int n = n0 + nf*16 + r;
    #pragma unroll
    for (int mf = 0; mf < 4; ++mf)
      #pragma unroll
      for (int j = 0; j < 4; ++j)
        dst[((size_t)sk*64 + (mf*16 + g*4 + j))*N + n] = acc[mf][nf][j];
  }
}

// ---------------- split-K reduce + bias + tanh -> bf16 ------------------------
__global__ void k_reduce(const float* __restrict__ part, const float* __restrict__ bias,
                         short* __restrict__ dstb, int N, int SK){
  size_t idx = (size_t)blockIdx.x*256 + threadIdx.x;
  if (idx >= (size_t)64*N) return;
  int b = (int)(idx / N), n = (int)(idx % N);
  float v = bias[n];
  for (int s = 0; s < SK; ++s) v += part[((size_t)s*64 + b)*N + n];
  dstb[(size_t)b*N + n] = f2bf(tanhf(v));
}

// ------ logits: D[64][50257] = A_bf16[64][1024] @ oW^T + ob -------------------
// LDS-staged, row-contiguous staging (1 KB/instr) + T14 async-STAGE split:
// issue chunk c+1's global loads BEFORE computing chunk c; ds_write after the
// read-done barrier. XOR-swizzled LDS (byte ^= (row&7)<<4).
__global__ __launch_bounds__(256)
void k_logits3(const short* __restrict__ A, const float* __restrict__ W,
               const float* __restrict__ bias, float* __restrict__ out)
{
  __shared__ short Wl[64 * 256];   // 32 KB
  const int tid = threadIdx.x;
  const int wave = tid >> 6, lane = tid & 63;
  const int r = lane & 15, g = lane >> 4;
  const int n0 = blockIdx.x * 64;
  const int myrow = wave*16 + r;           // LDS row holding my output col

#define LOADC(CC, ST) { _Pragma("unroll") \
    for (int rr = 0; rr < 16; ++rr) { \
      const int row = wave*16 + rr; \
      const int grow = (n0 + row < VV) ? (n0 + row) : (VV - 1); \
      ST[rr] = *(const float4*)(W + (size_t)grow*1024 + (CC)*256 + lane*4); \
    } }
#define WRITEC(ST) { _Pragma("unroll") \
    for (int rr = 0; rr < 16; ++rr) { \
      const int row = wave*16 + rr; \
      short4 s4; \
      s4.x = f2bf(ST[rr].x); s4.y = f2bf(ST[rr].y); \
      s4.z = f2bf(ST[rr].z); s4.w = f2bf(ST[rr].w); \
      *(short4*)((char*)Wl + ((row*512 + lane*8) ^ ((row&7)<<4))) = s4; \
    } }

  f32x4 acc[4] = {};
  {
    float4 st[16];
    LOADC(0, st);
    WRITEC(st);
  }
  __syncthreads();

  for (int c = 0; c < 4; ++c) {
    float4 st2[16];
    if (c < 3) LOADC(c+1, st2);            // in flight during compute
    const int kc = c*256;
    #pragma unroll 4
    for (int ks = 0; ks < 8; ++ks) {
      const bf16x8 bfr = *(const bf16x8*)((char*)Wl +
            ((myrow*512 + ks*64 + g*16) ^ ((myrow&7)<<4)));
      const int kk = kc + ks*32 + g*8;
      #pragma unroll
      for (int mf = 0; mf < 4; ++mf) {
        const bf16x8 af = *(const bf16x8*)(A + (size_t)(mf*16 + r)*1024 + kk);
        acc[mf] = __builtin_amdgcn_mfma_f32_16x16x32_bf16(af, bfr, acc[mf], 0, 0, 0);
      }
    }
    __syncthreads();                       // all reads of Wl done
    if (c < 3) {
      WRITEC(st2);                         // waits vmcnt as needed
      __syncthreads();                     // writes visible
    }
  }
#undef LOADC
#undef WRITEC

  const int n = n0 + wave*16 + r;
  if (n < VV) {
    const float bv = bias[n];
    #pragma unroll
    for (int mf = 0; mf < 4; ++mf)
      #pragma unroll
      for (int j = 0; j < 4; ++j)
        out[(size_t)(mf*16 + g*4 + j)*VV + n] = acc[mf][j] + bv;
  }
}

// ---------------- attention pass 1: quarter-mapped lanes ----------------------
// Lane l owns elements {j*256 + l*4 + i} -> every enc load instruction is
// 64 lanes x 16 B = 1 KB CONTIGUOUS (the 6.3 TB/s pattern). No barriers in loop.
__global__ __launch_bounds__(256)
void k_attn_part(const float* __restrict__ h, const float* __restrict__ enc,
                 float* __restrict__ energ, float* __restrict__ mpart,
                 float* __restrict__ lpart, float* __restrict__ ctxpart, int C){
  const int b  = blockIdx.x & 63;
  const int ch = blockIdx.x >> 6;
  const int wave = threadIdx.x >> 6;
  const int lane = threadIdx.x & 63;
  const int rows = SS / C;
  const int rpw  = rows >> 2;
  const int sw = ch*rows + wave*rpw;

  float4 hq0, hq1, hq2, hq3;
  {
    const float* hb = h + (size_t)b*HH + lane*4;
    hq0 = *(const float4*)(hb);
    hq1 = *(const float4*)(hb + 256);
    hq2 = *(const float4*)(hb + 512);
    hq3 = *(const float4*)(hb + 768);
  }
  float m = -INFINITY, l = 0.f;
  float cacc[16];
  #pragma unroll
  for (int j = 0; j < 16; ++j) cacc[j] = 0.f;

  for (int i = 0; i < rpw; i += 2) {
    const float* ep = enc + ((size_t)(sw+i)*BB + b)*HH + lane*4;
    const float* fp = ep + (size_t)BB*HH;
    const float4 e0 = *(const float4*)(ep);
    const float4 e1 = *(const float4*)(ep + 256);
    const float4 e2 = *(const float4*)(ep + 512);
    const float4 e3 = *(const float4*)(ep + 768);
    const float4 f0 = *(const float4*)(fp);
    const float4 f1 = *(const float4*)(fp + 256);
    const float4 f2 = *(const float4*)(fp + 512);
    const float4 f3 = *(const float4*)(fp + 768);
    float p = hq0.x*e0.x + hq0.y*e0.y + hq0.z*e0.z + hq0.w*e0.w
            + hq1.x*e1.x + hq1.y*e1.y + hq1.z*e1.z + hq1.w*e1.w
            + hq2.x*e2.x + hq2.y*e2.y + hq2.z*e2.z + hq2.w*e2.w
            + hq3.x*e3.x + hq3.y*e3.y + hq3.z*e3.z + hq3.w*e3.w;
    float q = hq0.x*f0.x + hq0.y*f0.y + hq0.z*f0.z + hq0.w*f0.w
            + hq1.x*f1.x + hq1.y*f1.y + hq1.z*f1.z + hq1.w*f1.w
            + hq2.x*f2.x + hq2.y*f2.y + hq2.z*f2.z + hq2.w*f2.w
            + hq3.x*f3.x + hq3.y*f3.y + hq3.z*f3.z + hq3.w*f3.w;
    p += __shfl_xor(p, 1);  q += __shfl_xor(q, 1);
    p += __shfl_xor(p, 2);  q += __shfl_xor(q, 2);
    p += __shfl_xor(p, 4);  q += __shfl_xor(q, 4);
    p += __shfl_xor(p, 8);  q += __shfl_xor(q, 8);
    p += __shfl_xor(p, 16); q += __shfl_xor(q, 16);
    p += __shfl_xor(p, 32); q += __shfl_xor(q, 32);
    if (lane == 0) {
      float2 pq; pq.x = p; pq.y = q;
      *(float2*)(energ + (size_t)b*SS + sw + i) = pq;
    }
    const float mn = fmaxf(fmaxf(m, p), q);
    const float sc = __expf(m - mn);
    const float pe = __expf(p - mn);
    const float qe = __expf(q - mn);
    l = l*sc + pe + qe;
    cacc[0]  = cacc[0]*sc  + pe*e0.x + qe*f0.x;
    cacc[1]  = cacc[1]*sc  + pe*e0.y + qe*f0.y;
    cacc[2]  = cacc[2]*sc  + pe*e0.z + qe*f0.z;
    cacc[3]  = cacc[3]*sc  + pe*e0.w + qe*f0.w;
    cacc[4]  = cacc[4]*sc  + pe*e1.x + qe*f1.x;
    cacc[5]  = cacc[5]*sc  + pe*e1.y + qe*f1.y;
    cacc[6]  = cacc[6]*sc  + pe*e1.z + qe*f1.z;
    cacc[7]  = cacc[7]*sc  + pe*e1.w + qe*f1.w;
    cacc[8]  = cacc[8]*sc  + pe*e2.x + qe*f2.x;
    cacc[9]  = cacc[9]*sc  + pe*e2.y + qe*f2.y;
    cacc[10] = cacc[10]*sc + pe*e2.z + qe*f2.z;
    cacc[11] = cacc[11]*sc + pe*e2.w + qe*f2.w;
    cacc[12] = cacc[12]*sc + pe*e3.x + qe*f3.x;
    cacc[13] = cacc[13]*sc + pe*e3.y + qe*f3.y;
    cacc[14] = cacc[14]*sc + pe*e3.z + qe*f3.z;
    cacc[15] = cacc[15]*sc + pe*e3.w + qe*f3.w;
    m = mn;
  }

  // cross-wave combine; positions: j*256 + lane*4 + i (absolute layout)
  __shared__ float sm[4], sl[4];
  __shared__ float sctx[4][1024];
  if (lane == 0) { sm[wave] = m; sl[wave] = l; }
  __syncthreads();
  const float mg = fmaxf(fmaxf(sm[0], sm[1]), fmaxf(sm[2], sm[3]));
  const float lg = sl[0]*__expf(sm[0]-mg) + sl[1]*__expf(sm[1]-mg)
                 + sl[2]*__expf(sm[2]-mg) + sl[3]*__expf(sm[3]-mg);
  const float scw = __expf(m - mg);
  #pragma unroll
  for (int j = 0; j < 4; ++j) {
    float4 v;
    v.x = cacc[j*4+0]*scw; v.y = cacc[j*4+1]*scw;
    v.z = cacc[j*4+2]*scw; v.w = cacc[j*4+3]*scw;
    *(float4*)&sctx[wave][j*256 + lane*4] = v;
  }
  __syncthreads();
  const int d = threadIdx.x * 4;
  const float4 a0 = *(const float4*)&sctx[0][d];
  const float4 a1 = *(const float4*)&sctx[1][d];
  const float4 a2 = *(const float4*)&sctx[2][d];
  const float4 a3 = *(const float4*)&sctx[3][d];
  float4 rr;
  rr.x = a0.x+a1.x+a2.x+a3.x; rr.y = a0.y+a1.y+a2.y+a3.y;
  rr.z = a0.z+a1.z+a2.z+a3.z; rr.w = a0.w+a1.w+a2.w+a3.w;
  *(float4*)(ctxpart + ((size_t)(b*C + ch))*HH + d) = rr;
  if (threadIdx.x == 0) { mpart[b*C+ch] = mg; lpart[b*C+ch] = lg; }
}

// ---------------- attention combine + ctx bf16 into concA[:,1024:2048] --------
__global__ void k_attn_fin(const float* __restrict__ mpart, const float* __restrict__ lpart,
                           const float* __restrict__ ctxpart, const float* __restrict__ energ,
                           float* __restrict__ attn, short* __restrict__ concA, int C){
  const int b = blockIdx.x, tid = threadIdx.x;
  float m = -INFINITY;
  for (int c = 0; c < C; ++c) m = fmaxf(m, mpart[b*C+c]);
  float l = 0.f;
  for (int c = 0; c < C; ++c) l += lpart[b*C+c] * __expf(mpart[b*C+c] - m);
  const float inv = 1.0f / l;
  float ax = 0.f, ay = 0.f, az = 0.f, aw = 0.f;
  for (int c = 0; c < C; ++c) {
    const float w = __expf(mpart[b*C+c] - m);
    const float* cp = ctxpart + ((size_t)(b*C+c))*HH + tid*4;
    ax += w*cp[0]; ay += w*cp[1]; az += w*cp[2]; aw += w*cp[3];
  }
  ax *= inv; ay *= inv; az *= inv; aw *= inv;
  short* ca = concA + (size_t)b*2048 + 1024 + tid*4;
  ca[0] = f2bf(ax); ca[1] = f2bf(ay); ca[2] = f2bf(az); ca[3] = f2bf(aw);
  for (int j = 0; j < 8; ++j) {
    const int s = j*256 + tid;
    attn[(size_t)b*SS + s] = __expf(energ[(size_t)b*SS + s] - m) * inv;
  }
}

extern "C" void kernel_launch(void* const* d_in, const int* in_sizes, int n_in,
                              void* d_out, int out_size, void* d_ws, size_t ws_size,
                              hipStream_t stream){
  const int*   seq  = (const int*)  d_in[0];
  const float* h0   = (const float*)d_in[1];
  const float* c0   = (const float*)d_in[2];
  const float* enc  = (const float*)d_in[3];
  const float* embW = (const float*)d_in[4];
  const float* W_ih = (const float*)d_in[5];
  const float* W_hh = (const float*)d_in[6];
  const float* b_ih = (const float*)d_in[7];
  const float* b_hh = (const float*)d_in[8];
  const float* cW   = (const float*)d_in[9];
  const float* cb   = (const float*)d_in[10];
  const float* oW   = (const float*)d_in[11];
  const float* ob   = (const float*)d_in[12];
  float* out = (float*)d_out;

  float* ws = (float*)d_ws;
  // ws layout (float offsets)
  const size_t o_energ = 0;            // 131072
  const size_t o_concA = 131072;       // 65536  (64x2048 bf16)
  const size_t o_concB = 196608;       // 32768  (64x1024 bf16)
  const size_t o_Ahi   = 229376;       // 65536  (64x2048 bf16)
  const size_t o_Alo   = 294912;       // 65536
  const size_t o_mp    = 360448;
  const size_t SKPART  = 4194304;      // 16*64*4096 fp32 partials
  int C = 32;
  for (;;) {
    size_t need = (o_mp + (size_t)64*C*2 + (size_t)64*C*1024 + SKPART) * sizeof(float);
    if (need <= ws_size || C == 1) break;
    C >>= 1;
  }
  float* energ   = ws + o_energ;
  short* concA   = (short*)(ws + o_concA);
  short* concB   = (short*)(ws + o_concB);
  short* Ahi     = (short*)(ws + o_Ahi);
  short* Alo     = (short*)(ws + o_Alo);
  float* mpart   = ws + o_mp;
  float* lpart   = mpart + (size_t)64*C;
  float* ctxpart = lpart + (size_t)64*C;
  float* skpart  = ctxpart + (size_t)64*C*1024;

  const size_t o_h = 3216448, o_c = 3281984, o_attn = 3347520;

  // A = [emb[seq] | h0] as bf16 hi/lo pair
  k_prep<<<64, 256, 0, stream>>>(seq, embW, h0, Ahi, Alo);
  // gates partials via pair-MFMA (split-K 16)
  k_gates<<<dim3(32,16), 256, 0, stream>>>(Ahi, Alo, W_ih, W_hh, skpart);
  // reduce + biases + LSTM pointwise -> h, c, concA[:, :1024] (bf16)
  k_rlstm<<<256, 256, 0, stream>>>(skpart, b_ih, b_hh, c0, out + o_h, out + o_c,
                                   concA, 16);
  // fused attention (single encoder read, 1 KB-contiguous instructions)
  k_attn_part<<<64*C, 256, 0, stream>>>(out + o_h, enc, energ, mpart, lpart, ctxpart, C);
  k_attn_fin<<<64, 256, 0, stream>>>(mpart, lpart, ctxpart, energ, out + o_attn, concA, C);
  // concat_out = tanh([h,ctx] @ cW^T + cb) -> bf16 (MFMA, split-K 16)
  k_mfma<<<dim3(8,16), 256, 0, stream>>>(concA, 2048, cW, 2048, skpart, 1024, 2048);
  k_reduce<<<256, 256, 0, stream>>>(skpart, cb, concB, 1024, 16);
  // logits = concat_out @ out_W^T + out_b  (row-contiguous staging + T14 overlap)
  k_logits3<<<786, 256, 0, stream>>>(concB, oW, ob, out);
}

// Round 11
// 262.627 us; speedup vs baseline: 1.1226x; 1.1226x over previous
//
#include <hip/hip_runtime.h>
#include <hip/hip_bf16.h>
#include <math.h>

#define BB 64
#define HH 1024
#define SS 2048
#define VV 50257

typedef float f32x4 __attribute__((ext_vector_type(4)));
typedef short bf16x8 __attribute__((ext_vector_type(8)));

__device__ __forceinline__ float sigf(float x){ return 1.0f/(1.0f+__expf(-x)); }
__device__ __forceinline__ short f2bf(float f){
  __hip_bfloat16 h = __float2bfloat16(f);
  return __builtin_bit_cast(short, h);
}
__device__ __forceinline__ float bf2f(short s){
  __hip_bfloat16 h = __builtin_bit_cast(__hip_bfloat16, s);
  return __bfloat162float(h);
}

// ------ prep: A = [emb[seq] | h0] split into bf16 hi/lo pair  [64][2048] -----
__global__ void k_prep(const int* __restrict__ seq, const float* __restrict__ embW,
                       const float* __restrict__ h0,
                       short* __restrict__ Ahi, short* __restrict__ Alo){
  const int b = blockIdx.x;
  const int k = threadIdx.x * 8;     // 0..2047
  const float* src = (k < 1024) ? (embW + (size_t)seq[b]*1024 + k)
                                : (h0 + (size_t)b*1024 + (k - 1024));
  float4 v0 = *(const float4*)src;
  float4 v1 = *(const float4*)(src + 4);
  float v[8] = {v0.x,v0.y,v0.z,v0.w,v1.x,v1.y,v1.z,v1.w};
  bf16x8 hi, lo;
  #pragma unroll
  for (int j = 0; j < 8; ++j) {
    short h = f2bf(v[j]);
    hi[j] = h;
    lo[j] = f2bf(v[j] - bf2f(h));
  }
  *(bf16x8*)(Ahi + (size_t)b*2048 + k) = hi;
  *(bf16x8*)(Alo + (size_t)b*2048 + k) = lo;
}

// ------ gates GEMM via bf16-pair MFMA: partials dst[sk][64][4096] ------------
__global__ __launch_bounds__(256, 3)
void k_gates(const short* __restrict__ Ahi, const short* __restrict__ Alo,
             const float* __restrict__ W_ih, const float* __restrict__ W_hh,
             float* __restrict__ dst)
{
  const int tid = threadIdx.x;
  const int wave = tid >> 6, lane = tid & 63;
  const int r = lane & 15, g = lane >> 4;
  const int nb = blockIdx.x, sk = blockIdx.y;
  const int n0 = nb*128 + wave*32;
  const int kbase = sk*128;
  const float* Wm = (kbase < 1024) ? W_ih : W_hh;
  const int kw = (kbase < 1024) ? kbase : (kbase - 1024);

  f32x4 acc[4][2] = {};

  #pragma unroll
  for (int ks = 0; ks < 4; ++ks) {
    const int kk = kbase + ks*32 + g*8;     // A offset
    const int ko = kw   + ks*32 + g*8;      // W offset
    bf16x8 ahi[4], alo[4];
    #pragma unroll
    for (int mf = 0; mf < 4; ++mf) {
      ahi[mf] = *(const bf16x8*)(Ahi + (size_t)(mf*16 + r)*2048 + kk);
      alo[mf] = *(const bf16x8*)(Alo + (size_t)(mf*16 + r)*2048 + kk);
    }
    #pragma unroll
    for (int nf = 0; nf < 2; ++nf) {
      const int n = n0 + nf*16 + r;
      const float* wp = Wm + (size_t)n*1024 + ko;
      float4 w0 = *(const float4*)wp;
      float4 w1 = *(const float4*)(wp + 4);
      float wv[8] = {w0.x,w0.y,w0.z,w0.w,w1.x,w1.y,w1.z,w1.w};
      bf16x8 whi, wlo;
      #pragma unroll
      for (int j = 0; j < 8; ++j) {
        short h = f2bf(wv[j]);
        whi[j] = h;
        wlo[j] = f2bf(wv[j] - bf2f(h));
      }
      #pragma unroll
      for (int mf = 0; mf < 4; ++mf) {
        acc[mf][nf] = __builtin_amdgcn_mfma_f32_16x16x32_bf16(ahi[mf], whi, acc[mf][nf], 0,0,0);
        acc[mf][nf] = __builtin_amdgcn_mfma_f32_16x16x32_bf16(alo[mf], whi, acc[mf][nf], 0,0,0);
        acc[mf][nf] = __builtin_amdgcn_mfma_f32_16x16x32_bf16(ahi[mf], wlo, acc[mf][nf], 0,0,0);
      }
    }
  }

  #pragma unroll
  for (int nf = 0; nf < 2; ++nf) {
    const int n = n0 + nf*16 + r;
    #pragma unroll
    for (int mf = 0; mf < 4; ++mf)
      #pragma unroll
      for (int j = 0; j < 4; ++j)
        dst[((size_t)sk*64 + (mf*16 + g*4 + j))*4096 + n] = acc[mf][nf][j];
  }
}

// -------- fused split-K reduce + bias + LSTM pointwise -> h, c, concA[:, :1024]
__global__ void k_rlstm(const float* __restrict__ part, const float* __restrict__ b_ih,
                        const float* __restrict__ b_hh, const float* __restrict__ c0,
                        float* __restrict__ h_out, float* __restrict__ c_out,
                        short* __restrict__ concA, int SK){
  int idx = blockIdx.x*256 + threadIdx.x;    // 64*1024
  int b = idx >> 10, k = idx & 1023;
  float gi = b_ih[k]      + b_hh[k];
  float gf = b_ih[1024+k] + b_hh[1024+k];
  float gg = b_ih[2048+k] + b_hh[2048+k];
  float go = b_ih[3072+k] + b_hh[3072+k];
  const float* p = part + (size_t)b*4096 + k;
  for (int s = 0; s < SK; ++s) {
    const float* ps = p + (size_t)s*64*4096;
    gi += ps[0]; gf += ps[1024]; gg += ps[2048]; go += ps[3072];
  }
  float c = sigf(gf)*c0[idx] + sigf(gi)*tanhf(gg);
  float h = sigf(go)*tanhf(c);
  c_out[idx] = c;
  h_out[idx] = h;
  concA[(size_t)b*2048 + k] = f2bf(h);
}

// ---------------- streaming bf16 MFMA GEMM (concat): partials dst[sk][64][N] --
__global__ __launch_bounds__(256)
void k_mfma(const short* __restrict__ A, int lda,
            const float* __restrict__ W1, int ldw,
            float* __restrict__ dst, int N, int Ktot)
{
  const int tid  = threadIdx.x;
  const int wave = tid >> 6, lane = tid & 63;
  const int nb = blockIdx.x, sk = blockIdx.y, SK = gridDim.y;
  const int ksteps = Ktot >> 5;
  const int kps = ksteps / SK;
  const int k0 = sk * kps;
  const int n0 = nb*128 + wave*32;
  const int r = lane & 15, g = lane >> 4;

  f32x4 acc[4][2] = {};

  for (int ks = k0; ks < k0 + kps; ++ks) {
    const int kk = (ks << 5) + g*8;
    bf16x8 af[4];
    #pragma unroll
    for (int mf = 0; mf < 4; ++mf)
      af[mf] = *(const bf16x8*)(A + (size_t)(mf*16 + r)*lda + kk);
    #pragma unroll
    for (int nf = 0; nf < 2; ++nf) {
      const int n = n0 + nf*16 + r;
      const float* wp = W1 + (size_t)n*ldw + kk;
      float4 w0 = *(const float4*)wp;
      float4 w1 = *(const float4*)(wp + 4);
      bf16x8 bfr;
      bfr[0]=f2bf(w0.x); bfr[1]=f2bf(w0.y); bfr[2]=f2bf(w0.z); bfr[3]=f2bf(w0.w);
      bfr[4]=f2bf(w1.x); bfr[5]=f2bf(w1.y); bfr[6]=f2bf(w1.z); bfr[7]=f2bf(w1.w);
      #pragma unroll
      for (int mf = 0; mf < 4; ++mf)
        acc[mf][nf] = __builtin_amdgcn_mfma_f32_16x16x32_bf16(af[mf], bfr, acc[mf][nf], 0, 0, 0);
    }
  }

  #pragma unroll
  for (int nf = 0; nf < 2; ++nf) {
    const int n = n0 + nf*16 + r;
    #pragma unroll
    for (int mf = 0; mf < 4; ++mf)
      #pragma unroll
      for (int j = 0; j < 4; ++j)
        dst[((size_t)sk*64 + (mf*16 + g*4 + j))*N + n] = acc[mf][nf][j];
  }
}

// ---------------- split-K reduce + bias + tanh -> bf16 ------------------------
__global__ void k_reduce(const float* __restrict__ part, const float* __restrict__ bias,
                         short* __restrict__ dstb, int N, int SK){
  size_t idx = (size_t)blockIdx.x*256 + threadIdx.x;
  if (idx >= (size_t)64*N) return;
  int b = (int)(idx / N), n = (int)(idx % N);
  float v = bias[n];
  for (int s = 0; s < SK; ++s) v += part[((size_t)s*64 + b)*N + n];
  dstb[(size_t)b*N + n] = f2bf(tanhf(v));
}

// ------ logits: D[64][50257] = A_bf16[64][1024] @ oW^T + ob -------------------
// Direct-streaming MFMA (R4 structure) with 4-way in-block K-split: block = 32
// cols; wave kh owns K quarter kb=kh*256; 4-wave LDS reduce. Grid 1571 blocks
// -> ~24 waves/CU of in-flight W streams (2x R4's concurrency).
__global__ __launch_bounds__(256)
void k_logits4(const short* __restrict__ A, const float* __restrict__ W,
               const float* __restrict__ bias, float* __restrict__ out)
{
  __shared__ float red[4][32][64];   // 32 KB
  const int tid = threadIdx.x;
  const int wave = tid >> 6, lane = tid & 63;
  const int r = lane & 15, g = lane >> 4;
  const int n0 = blockIdx.x * 32;
  const int nA = n0 + r, nB = n0 + 16 + r;
  const int nAc = (nA < VV) ? nA : (VV - 1);
  const int nBc = (nB < VV) ? nB : (VV - 1);
  const int kb = wave * 256;

  const short* A0 = A + (size_t)r*1024 + kb + g*8;
  const float* wA = W + (size_t)nAc*1024 + kb + g*8;
  const float* wB = W + (size_t)nBc*1024 + kb + g*8;

  f32x4 acc[4][2] = {};

  #pragma unroll
  for (int ks = 0; ks < 8; ++ks) {
    const int o = ks*32;
    const float4 u0 = *(const float4*)(wA + o);
    const float4 u1 = *(const float4*)(wA + o + 4);
    const float4 v0 = *(const float4*)(wB + o);
    const float4 v1 = *(const float4*)(wB + o + 4);
    bf16x8 bA, bB;
    bA[0]=f2bf(u0.x); bA[1]=f2bf(u0.y); bA[2]=f2bf(u0.z); bA[3]=f2bf(u0.w);
    bA[4]=f2bf(u1.x); bA[5]=f2bf(u1.y); bA[6]=f2bf(u1.z); bA[7]=f2bf(u1.w);
    bB[0]=f2bf(v0.x); bB[1]=f2bf(v0.y); bB[2]=f2bf(v0.z); bB[3]=f2bf(v0.w);
    bB[4]=f2bf(v1.x); bB[5]=f2bf(v1.y); bB[6]=f2bf(v1.z); bB[7]=f2bf(v1.w);
    #pragma unroll
    for (int mf = 0; mf < 4; ++mf) {
      const bf16x8 af = *(const bf16x8*)(A0 + (size_t)mf*16*1024 + o);
      acc[mf][0] = __builtin_amdgcn_mfma_f32_16x16x32_bf16(af, bA, acc[mf][0], 0,0,0);
      acc[mf][1] = __builtin_amdgcn_mfma_f32_16x16x32_bf16(af, bB, acc[mf][1], 0,0,0);
    }
  }

  // deposit all 4 waves' partials
  #pragma unroll
  for (int nf = 0; nf < 2; ++nf)
    #pragma unroll
    for (int mf = 0; mf < 4; ++mf)
      #pragma unroll
      for (int j = 0; j < 4; ++j)
        red[wave][nf*16 + mf*4 + j][lane] = acc[mf][nf][j];
  __syncthreads();

  // each wave reduces 8 of the 32 (row,colgroup) values and writes
  #pragma unroll
  for (int vi = 0; vi < 8; ++vi) {
    const int v  = wave*8 + vi;
    const int nf = v >> 4, mf = (v >> 2) & 3, j = v & 3;
    const float s = red[0][v][lane] + red[1][v][lane]
                  + red[2][v][lane] + red[3][v][lane];
    const int col = n0 + nf*16 + r;
    if (col < VV)
      out[(size_t)(mf*16 + g*4 + j)*VV + col] = s + bias[col];
  }
}

// ---------------- attention pass 1: quarter-mapped lanes ----------------------
// Lane l owns elements {j*256 + l*4 + i} -> every enc load instruction is
// 64 lanes x 16 B = 1 KB CONTIGUOUS (m13's 6.3 TB/s pattern). No barriers in loop.
__global__ __launch_bounds__(256)
void k_attn_part(const float* __restrict__ h, const float* __restrict__ enc,
                 float* __restrict__ energ, float* __restrict__ mpart,
                 float* __restrict__ lpart, float* __restrict__ ctxpart, int C){
  const int b  = blockIdx.x & 63;
  const int ch = blockIdx.x >> 6;
  const int wave = threadIdx.x >> 6;
  const int lane = threadIdx.x & 63;
  const int rows = SS / C;
  const int rpw  = rows >> 2;
  const int sw = ch*rows + wave*rpw;

  float4 hq0, hq1, hq2, hq3;
  {
    const float* hb = h + (size_t)b*HH + lane*4;
    hq0 = *(const float4*)(hb);
    hq1 = *(const float4*)(hb + 256);
    hq2 = *(const float4*)(hb + 512);
    hq3 = *(const float4*)(hb + 768);
  }
  float m = -INFINITY, l = 0.f;
  float cacc[16];
  #pragma unroll
  for (int j = 0; j < 16; ++j) cacc[j] = 0.f;

  for (int i = 0; i < rpw; i += 2) {
    const float* ep = enc + ((size_t)(sw+i)*BB + b)*HH + lane*4;
    const float* fp = ep + (size_t)BB*HH;
    const float4 e0 = *(const float4*)(ep);
    const float4 e1 = *(const float4*)(ep + 256);
    const float4 e2 = *(const float4*)(ep + 512);
    const float4 e3 = *(const float4*)(ep + 768);
    const float4 f0 = *(const float4*)(fp);
    const float4 f1 = *(const float4*)(fp + 256);
    const float4 f2 = *(const float4*)(fp + 512);
    const float4 f3 = *(const float4*)(fp + 768);
    float p = hq0.x*e0.x + hq0.y*e0.y + hq0.z*e0.z + hq0.w*e0.w
            + hq1.x*e1.x + hq1.y*e1.y + hq1.z*e1.z + hq1.w*e1.w
            + hq2.x*e2.x + hq2.y*e2.y + hq2.z*e2.z + hq2.w*e2.w
            + hq3.x*e3.x + hq3.y*e3.y + hq3.z*e3.z + hq3.w*e3.w;
    float q = hq0.x*f0.x + hq0.y*f0.y + hq0.z*f0.z + hq0.w*f0.w
            + hq1.x*f1.x + hq1.y*f1.y + hq1.z*f1.z + hq1.w*f1.w
            + hq2.x*f2.x + hq2.y*f2.y + hq2.z*f2.z + hq2.w*f2.w
            + hq3.x*f3.x + hq3.y*f3.y + hq3.z*f3.z + hq3.w*f3.w;
    p += __shfl_xor(p, 1);  q += __shfl_xor(q, 1);
    p += __shfl_xor(p, 2);  q += __shfl_xor(q, 2);
    p += __shfl_xor(p, 4);  q += __shfl_xor(q, 4);
    p += __shfl_xor(p, 8);  q += __shfl_xor(q, 8);
    p += __shfl_xor(p, 16); q += __shfl_xor(q, 16);
    p += __shfl_xor(p, 32); q += __shfl_xor(q, 32);
    if (lane == 0) {
      float2 pq; pq.x = p; pq.y = q;
      *(float2*)(energ + (size_t)b*SS + sw + i) = pq;
    }
    const float mn = fmaxf(fmaxf(m, p), q);
    const float sc = __expf(m - mn);
    const float pe = __expf(p - mn);
    const float qe = __expf(q - mn);
    l = l*sc + pe + qe;
    cacc[0]  = cacc[0]*sc  + pe*e0.x + qe*f0.x;
    cacc[1]  = cacc[1]*sc  + pe*e0.y + qe*f0.y;
    cacc[2]  = cacc[2]*sc  + pe*e0.z + qe*f0.z;
    cacc[3]  = cacc[3]*sc  + pe*e0.w + qe*f0.w;
    cacc[4]  = cacc[4]*sc  + pe*e1.x + qe*f1.x;
    cacc[5]  = cacc[5]*sc  + pe*e1.y + qe*f1.y;
    cacc[6]  = cacc[6]*sc  + pe*e1.z + qe*f1.z;
    cacc[7]  = cacc[7]*sc  + pe*e1.w + qe*f1.w;
    cacc[8]  = cacc[8]*sc  + pe*e2.x + qe*f2.x;
    cacc[9]  = cacc[9]*sc  + pe*e2.y + qe*f2.y;
    cacc[10] = cacc[10]*sc + pe*e2.z + qe*f2.z;
    cacc[11] = cacc[11]*sc + pe*e2.w + qe*f2.w;
    cacc[12] = cacc[12]*sc + pe*e3.x + qe*f3.x;
    cacc[13] = cacc[13]*sc + pe*e3.y + qe*f3.y;
    cacc[14] = cacc[14]*sc + pe*e3.z + qe*f3.z;
    cacc[15] = cacc[15]*sc + pe*e3.w + qe*f3.w;
    m = mn;
  }

  // cross-wave combine; positions: j*256 + lane*4 + i (absolute layout)
  __shared__ float sm[4], sl[4];
  __shared__ float sctx[4][1024];
  if (lane == 0) { sm[wave] = m; sl[wave] = l; }
  __syncthreads();
  const float mg = fmaxf(fmaxf(sm[0], sm[1]), fmaxf(sm[2], sm[3]));
  const float lg = sl[0]*__expf(sm[0]-mg) + sl[1]*__expf(sm[1]-mg)
                 + sl[2]*__expf(sm[2]-mg) + sl[3]*__expf(sm[3]-mg);
  const float scw = __expf(m - mg);
  #pragma unroll
  for (int j = 0; j < 4; ++j) {
    float4 v;
    v.x = cacc[j*4+0]*scw; v.y = cacc[j*4+1]*scw;
    v.z = cacc[j*4+2]*scw; v.w = cacc[j*4+3]*scw;
    *(float4*)&sctx[wave][j*256 + lane*4] = v;
  }
  __syncthreads();
  const int d = threadIdx.x * 4;
  const float4 a0 = *(const float4*)&sctx[0][d];
  const float4 a1 = *(const float4*)&sctx[1][d];
  const float4 a2 = *(const float4*)&sctx[2][d];
  const float4 a3 = *(const float4*)&sctx[3][d];
  float4 rr;
  rr.x = a0.x+a1.x+a2.x+a3.x; rr.y = a0.y+a1.y+a2.y+a3.y;
  rr.z = a0.z+a1.z+a2.z+a3.z; rr.w = a0.w+a1.w+a2.w+a3.w;
  *(float4*)(ctxpart + ((size_t)(b*C + ch))*HH + d) = rr;
  if (threadIdx.x == 0) { mpart[b*C+ch] = mg; lpart[b*C+ch] = lg; }
}

// ---------------- attention combine + ctx bf16 into concA[:,1024:2048] --------
__global__ void k_attn_fin(const float* __restrict__ mpart, const float* __restrict__ lpart,
                           const float* __restrict__ ctxpart, const float* __restrict__ energ,
                           float* __restrict__ attn, short* __restrict__ concA, int C){
  const int b = blockIdx.x, tid = threadIdx.x;
  float m = -INFINITY;
  for (int c = 0; c < C; ++c) m = fmaxf(m, mpart[b*C+c]);
  float l = 0.f;
  for (int c = 0; c < C; ++c) l += lpart[b*C+c] * __expf(mpart[b*C+c] - m);
  const float inv = 1.0f / l;
  float ax = 0.f, ay = 0.f, az = 0.f, aw = 0.f;
  for (int c = 0; c < C; ++c) {
    const float w = __expf(mpart[b*C+c] - m);
    const float* cp = ctxpart + ((size_t)(b*C+c))*HH + tid*4;
    ax += w*cp[0]; ay += w*cp[1]; az += w*cp[2]; aw += w*cp[3];
  }
  ax *= inv; ay *= inv; az *= inv; aw *= inv;
  short* ca = concA + (size_t)b*2048 + 1024 + tid*4;
  ca[0] = f2bf(ax); ca[1] = f2bf(ay); ca[2] = f2bf(az); ca[3] = f2bf(aw);
  for (int j = 0; j < 8; ++j) {
    const int s = j*256 + tid;
    attn[(size_t)b*SS + s] = __expf(energ[(size_t)b*SS + s] - m) * inv;
  }
}

extern "C" void kernel_launch(void* const* d_in, const int* in_sizes, int n_in,
                              void* d_out, int out_size, void* d_ws, size_t ws_size,
                              hipStream_t stream){
  const int*   seq  = (const int*)  d_in[0];
  const float* h0   = (const float*)d_in[1];
  const float* c0   = (const float*)d_in[2];
  const float* enc  = (const float*)d_in[3];
  const float* embW = (const float*)d_in[4];
  const float* W_ih = (const float*)d_in[5];
  const float* W_hh = (const float*)d_in[6];
  const float* b_ih = (const float*)d_in[7];
  const float* b_hh = (const float*)d_in[8];
  const float* cW   = (const float*)d_in[9];
  const float* cb   = (const float*)d_in[10];
  const float* oW   = (const float*)d_in[11];
  const float* ob   = (const float*)d_in[12];
  float* out = (float*)d_out;

  float* ws = (float*)d_ws;
  // ws layout (float offsets)
  const size_t o_energ = 0;            // 131072
  const size_t o_concA = 131072;       // 65536  (64x2048 bf16)
  const size_t o_concB = 196608;       // 32768  (64x1024 bf16)
  const size_t o_Ahi   = 229376;       // 65536  (64x2048 bf16)
  const size_t o_Alo   = 294912;       // 65536
  const size_t o_mp    = 360448;
  const size_t SKPART  = 4194304;      // 16*64*4096 fp32 partials
  int C = 32;
  for (;;) {
    size_t need = (o_mp + (size_t)64*C*2 + (size_t)64*C*1024 + SKPART) * sizeof(float);
    if (need <= ws_size || C == 1) break;
    C >>= 1;
  }
  float* energ   = ws + o_energ;
  short* concA   = (short*)(ws + o_concA);
  short* concB   = (short*)(ws + o_concB);
  short* Ahi     = (short*)(ws + o_Ahi);
  short* Alo     = (short*)(ws + o_Alo);
  float* mpart   = ws + o_mp;
  float* lpart   = mpart + (size_t)64*C;
  float* ctxpart = lpart + (size_t)64*C;
  float* skpart  = ctxpart + (size_t)64*C*1024;

  const size_t o_h = 3216448, o_c = 3281984, o_attn = 3347520;

  // A = [emb[seq] | h0] as bf16 hi/lo pair
  k_prep<<<64, 256, 0, stream>>>(seq, embW, h0, Ahi, Alo);
  // gates partials via pair-MFMA (split-K 16)
  k_gates<<<dim3(32,16), 256, 0, stream>>>(Ahi, Alo, W_ih, W_hh, skpart);
  // reduce + biases + LSTM pointwise -> h, c, concA[:, :1024] (bf16)
  k_rlstm<<<256, 256, 0, stream>>>(skpart, b_ih, b_hh, c0, out + o_h, out + o_c,
                                   concA, 16);
  // fused attention (single encoder read, 1 KB-contiguous instructions)
  k_attn_part<<<64*C, 256, 0, stream>>>(out + o_h, enc, energ, mpart, lpart, ctxpart, C);
  k_attn_fin<<<64, 256, 0, stream>>>(mpart, lpart, ctxpart, energ, out + o_attn, concA, C);
  // concat_out = tanh([h,ctx] @ cW^T + cb) -> bf16 (MFMA, split-K 16)
  k_mfma<<<dim3(8,16), 256, 0, stream>>>(concA, 2048, cW, 2048, skpart, 1024, 2048);
  k_reduce<<<256, 256, 0, stream>>>(skpart, cb, concB, 1024, 16);
  // logits = concat_out @ out_W^T + out_b  (4-way in-block K-split, 1571 blocks)
  k_logits4<<<1571, 256, 0, stream>>>(concB, oW, ob, out);
}

// Round 12
// 252.967 us; speedup vs baseline: 1.1655x; 1.0382x over previous
//
#include <hip/hip_runtime.h>
#include <hip/hip_bf16.h>
#include <math.h>

#define BB 64
#define HH 1024
#define SS 2048
#define VV 50257

typedef float f32x4 __attribute__((ext_vector_type(4)));
typedef short bf16x8 __attribute__((ext_vector_type(8)));

__device__ __forceinline__ float sigf(float x){ return 1.0f/(1.0f+__expf(-x)); }
__device__ __forceinline__ short f2bf(float f){
  __hip_bfloat16 h = __float2bfloat16(f);
  return __builtin_bit_cast(short, h);
}
__device__ __forceinline__ float bf2f(short s){
  __hip_bfloat16 h = __builtin_bit_cast(__hip_bfloat16, s);
  return __bfloat162float(h);
}
// non-temporal 16B load (L2/L3 no-allocate hint) for single-use streams
__device__ __forceinline__ f32x4 ntl4(const float* p){
  return __builtin_nontemporal_load((const f32x4*)p);
}

// ------ prep: A = [emb[seq] | h0] split into bf16 hi/lo pair  [64][2048] -----
__global__ void k_prep(const int* __restrict__ seq, const float* __restrict__ embW,
                       const float* __restrict__ h0,
                       short* __restrict__ Ahi, short* __restrict__ Alo){
  const int b = blockIdx.x;
  const int k = threadIdx.x * 8;     // 0..2047
  const float* src = (k < 1024) ? (embW + (size_t)seq[b]*1024 + k)
                                : (h0 + (size_t)b*1024 + (k - 1024));
  float4 v0 = *(const float4*)src;
  float4 v1 = *(const float4*)(src + 4);
  float v[8] = {v0.x,v0.y,v0.z,v0.w,v1.x,v1.y,v1.z,v1.w};
  bf16x8 hi, lo;
  #pragma unroll
  for (int j = 0; j < 8; ++j) {
    short h = f2bf(v[j]);
    hi[j] = h;
    lo[j] = f2bf(v[j] - bf2f(h));
  }
  *(bf16x8*)(Ahi + (size_t)b*2048 + k) = hi;
  *(bf16x8*)(Alo + (size_t)b*2048 + k) = lo;
}

// ------ gates GEMM via bf16-pair MFMA: partials dst[sk][64][4096] ------------
__global__ __launch_bounds__(256, 3)
void k_gates(const short* __restrict__ Ahi, const short* __restrict__ Alo,
             const float* __restrict__ W_ih, const float* __restrict__ W_hh,
             float* __restrict__ dst)
{
  const int tid = threadIdx.x;
  const int wave = tid >> 6, lane = tid & 63;
  const int r = lane & 15, g = lane >> 4;
  const int nb = blockIdx.x, sk = blockIdx.y;
  const int n0 = nb*128 + wave*32;
  const int kbase = sk*128;
  const float* Wm = (kbase < 1024) ? W_ih : W_hh;
  const int kw = (kbase < 1024) ? kbase : (kbase - 1024);

  f32x4 acc[4][2] = {};

  #pragma unroll
  for (int ks = 0; ks < 4; ++ks) {
    const int kk = kbase + ks*32 + g*8;     // A offset
    const int ko = kw   + ks*32 + g*8;      // W offset
    bf16x8 ahi[4], alo[4];
    #pragma unroll
    for (int mf = 0; mf < 4; ++mf) {
      ahi[mf] = *(const bf16x8*)(Ahi + (size_t)(mf*16 + r)*2048 + kk);
      alo[mf] = *(const bf16x8*)(Alo + (size_t)(mf*16 + r)*2048 + kk);
    }
    #pragma unroll
    for (int nf = 0; nf < 2; ++nf) {
      const int n = n0 + nf*16 + r;
      const float* wp = Wm + (size_t)n*1024 + ko;
      float4 w0 = *(const float4*)wp;
      float4 w1 = *(const float4*)(wp + 4);
      float wv[8] = {w0.x,w0.y,w0.z,w0.w,w1.x,w1.y,w1.z,w1.w};
      bf16x8 whi, wlo;
      #pragma unroll
      for (int j = 0; j < 8; ++j) {
        short h = f2bf(wv[j]);
        whi[j] = h;
        wlo[j] = f2bf(wv[j] - bf2f(h));
      }
      #pragma unroll
      for (int mf = 0; mf < 4; ++mf) {
        acc[mf][nf] = __builtin_amdgcn_mfma_f32_16x16x32_bf16(ahi[mf], whi, acc[mf][nf], 0,0,0);
        acc[mf][nf] = __builtin_amdgcn_mfma_f32_16x16x32_bf16(alo[mf], whi, acc[mf][nf], 0,0,0);
        acc[mf][nf] = __builtin_amdgcn_mfma_f32_16x16x32_bf16(ahi[mf], wlo, acc[mf][nf], 0,0,0);
      }
    }
  }

  #pragma unroll
  for (int nf = 0; nf < 2; ++nf) {
    const int n = n0 + nf*16 + r;
    #pragma unroll
    for (int mf = 0; mf < 4; ++mf)
      #pragma unroll
      for (int j = 0; j < 4; ++j)
        dst[((size_t)sk*64 + (mf*16 + g*4 + j))*4096 + n] = acc[mf][nf][j];
  }
}

// -------- fused split-K reduce + bias + LSTM pointwise -> h, c, concA[:, :1024]
__global__ void k_rlstm(const float* __restrict__ part, const float* __restrict__ b_ih,
                        const float* __restrict__ b_hh, const float* __restrict__ c0,
                        float* __restrict__ h_out, float* __restrict__ c_out,
                        short* __restrict__ concA, int SK){
  int idx = blockIdx.x*256 + threadIdx.x;    // 64*1024
  int b = idx >> 10, k = idx & 1023;
  float gi = b_ih[k]      + b_hh[k];
  float gf = b_ih[1024+k] + b_hh[1024+k];
  float gg = b_ih[2048+k] + b_hh[2048+k];
  float go = b_ih[3072+k] + b_hh[3072+k];
  const float* p = part + (size_t)b*4096 + k;
  for (int s = 0; s < SK; ++s) {
    const float* ps = p + (size_t)s*64*4096;
    gi += ps[0]; gf += ps[1024]; gg += ps[2048]; go += ps[3072];
  }
  float c = sigf(gf)*c0[idx] + sigf(gi)*tanhf(gg);
  float h = sigf(go)*tanhf(c);
  c_out[idx] = c;
  h_out[idx] = h;
  concA[(size_t)b*2048 + k] = f2bf(h);
}

// ---------------- streaming bf16 MFMA GEMM (concat): partials dst[sk][64][N] --
__global__ __launch_bounds__(256)
void k_mfma(const short* __restrict__ A, int lda,
            const float* __restrict__ W1, int ldw,
            float* __restrict__ dst, int N, int Ktot)
{
  const int tid  = threadIdx.x;
  const int wave = tid >> 6, lane = tid & 63;
  const int nb = blockIdx.x, sk = blockIdx.y, SK = gridDim.y;
  const int ksteps = Ktot >> 5;
  const int kps = ksteps / SK;
  const int k0 = sk * kps;
  const int n0 = nb*128 + wave*32;
  const int r = lane & 15, g = lane >> 4;

  f32x4 acc[4][2] = {};

  for (int ks = k0; ks < k0 + kps; ++ks) {
    const int kk = (ks << 5) + g*8;
    bf16x8 af[4];
    #pragma unroll
    for (int mf = 0; mf < 4; ++mf)
      af[mf] = *(const bf16x8*)(A + (size_t)(mf*16 + r)*lda + kk);
    #pragma unroll
    for (int nf = 0; nf < 2; ++nf) {
      const int n = n0 + nf*16 + r;
      const float* wp = W1 + (size_t)n*ldw + kk;
      float4 w0 = *(const float4*)wp;
      float4 w1 = *(const float4*)(wp + 4);
      bf16x8 bfr;
      bfr[0]=f2bf(w0.x); bfr[1]=f2bf(w0.y); bfr[2]=f2bf(w0.z); bfr[3]=f2bf(w0.w);
      bfr[4]=f2bf(w1.x); bfr[5]=f2bf(w1.y); bfr[6]=f2bf(w1.z); bfr[7]=f2bf(w1.w);
      #pragma unroll
      for (int mf = 0; mf < 4; ++mf)
        acc[mf][nf] = __builtin_amdgcn_mfma_f32_16x16x32_bf16(af[mf], bfr, acc[mf][nf], 0, 0, 0);
    }
  }

  #pragma unroll
  for (int nf = 0; nf < 2; ++nf) {
    const int n = n0 + nf*16 + r;
    #pragma unroll
    for (int mf = 0; mf < 4; ++mf)
      #pragma unroll
      for (int j = 0; j < 4; ++j)
        dst[((size_t)sk*64 + (mf*16 + g*4 + j))*N + n] = acc[mf][nf][j];
  }
}

// ---------------- split-K reduce + bias + tanh -> bf16 ------------------------
__global__ void k_reduce(const float* __restrict__ part, const float* __restrict__ bias,
                         short* __restrict__ dstb, int N, int SK){
  size_t idx = (size_t)blockIdx.x*256 + threadIdx.x;
  if (idx >= (size_t)64*N) return;
  int b = (int)(idx / N), n = (int)(idx % N);
  float v = bias[n];
  for (int s = 0; s < SK; ++s) v += part[((size_t)s*64 + b)*N + n];
  dstb[(size_t)b*N + n] = f2bf(tanhf(v));
}

// ------ logits: D[64][50257] = A_bf16[64][1024] @ oW^T + ob -------------------
// Direct-streaming MFMA, 4-way in-block K-split, W loads NON-TEMPORAL
// (single-use stream; bypass L2/L3 allocation). A stays cacheable (128 KB).
__global__ __launch_bounds__(256)
void k_logits4(const short* __restrict__ A, const float* __restrict__ W,
               const float* __restrict__ bias, float* __restrict__ out)
{
  __shared__ float red[4][32][64];   // 32 KB
  const int tid = threadIdx.x;
  const int wave = tid >> 6, lane = tid & 63;
  const int r = lane & 15, g = lane >> 4;
  const int n0 = blockIdx.x * 32;
  const int nA = n0 + r, nB = n0 + 16 + r;
  const int nAc = (nA < VV) ? nA : (VV - 1);
  const int nBc = (nB < VV) ? nB : (VV - 1);
  const int kb = wave * 256;

  const short* A0 = A + (size_t)r*1024 + kb + g*8;
  const float* wA = W + (size_t)nAc*1024 + kb + g*8;
  const float* wB = W + (size_t)nBc*1024 + kb + g*8;

  f32x4 acc[4][2] = {};

  #pragma unroll
  for (int ks = 0; ks < 8; ++ks) {
    const int o = ks*32;
    const f32x4 u0 = ntl4(wA + o);
    const f32x4 u1 = ntl4(wA + o + 4);
    const f32x4 v0 = ntl4(wB + o);
    const f32x4 v1 = ntl4(wB + o + 4);
    bf16x8 bA, bB;
    bA[0]=f2bf(u0.x); bA[1]=f2bf(u0.y); bA[2]=f2bf(u0.z); bA[3]=f2bf(u0.w);
    bA[4]=f2bf(u1.x); bA[5]=f2bf(u1.y); bA[6]=f2bf(u1.z); bA[7]=f2bf(u1.w);
    bB[0]=f2bf(v0.x); bB[1]=f2bf(v0.y); bB[2]=f2bf(v0.z); bB[3]=f2bf(v0.w);
    bB[4]=f2bf(v1.x); bB[5]=f2bf(v1.y); bB[6]=f2bf(v1.z); bB[7]=f2bf(v1.w);
    #pragma unroll
    for (int mf = 0; mf < 4; ++mf) {
      const bf16x8 af = *(const bf16x8*)(A0 + (size_t)mf*16*1024 + o);
      acc[mf][0] = __builtin_amdgcn_mfma_f32_16x16x32_bf16(af, bA, acc[mf][0], 0,0,0);
      acc[mf][1] = __builtin_amdgcn_mfma_f32_16x16x32_bf16(af, bB, acc[mf][1], 0,0,0);
    }
  }

  // deposit all 4 waves' partials
  #pragma unroll
  for (int nf = 0; nf < 2; ++nf)
    #pragma unroll
    for (int mf = 0; mf < 4; ++mf)
      #pragma unroll
      for (int j = 0; j < 4; ++j)
        red[wave][nf*16 + mf*4 + j][lane] = acc[mf][nf][j];
  __syncthreads();

  // each wave reduces 8 of the 32 (row,colgroup) values and writes
  #pragma unroll
  for (int vi = 0; vi < 8; ++vi) {
    const int v  = wave*8 + vi;
    const int nf = v >> 4, mf = (v >> 2) & 3, j = v & 3;
    const float s = red[0][v][lane] + red[1][v][lane]
                  + red[2][v][lane] + red[3][v][lane];
    const int col = n0 + nf*16 + r;
    if (col < VV)
      out[(size_t)(mf*16 + g*4 + j)*VV + col] = s + bias[col];
  }
}

// ---------------- attention pass 1: quarter-mapped lanes, NT enc loads --------
// Lane l owns elements {j*256 + l*4 + i}; each enc load instruction is 1 KB
// contiguous AND non-temporal (enc is single-use per pass; bypass allocation).
__global__ __launch_bounds__(256)
void k_attn_part(const float* __restrict__ h, const float* __restrict__ enc,
                 float* __restrict__ energ, float* __restrict__ mpart,
                 float* __restrict__ lpart, float* __restrict__ ctxpart, int C){
  const int b  = blockIdx.x & 63;
  const int ch = blockIdx.x >> 6;
  const int wave = threadIdx.x >> 6;
  const int lane = threadIdx.x & 63;
  const int rows = SS / C;
  const int rpw  = rows >> 2;
  const int sw = ch*rows + wave*rpw;

  f32x4 hq0, hq1, hq2, hq3;
  {
    const float* hb = h + (size_t)b*HH + lane*4;
    hq0 = *(const f32x4*)(hb);
    hq1 = *(const f32x4*)(hb + 256);
    hq2 = *(const f32x4*)(hb + 512);
    hq3 = *(const f32x4*)(hb + 768);
  }
  float m = -INFINITY, l = 0.f;
  float cacc[16];
  #pragma unroll
  for (int j = 0; j < 16; ++j) cacc[j] = 0.f;

  for (int i = 0; i < rpw; i += 2) {
    const float* ep = enc + ((size_t)(sw+i)*BB + b)*HH + lane*4;
    const float* fp = ep + (size_t)BB*HH;
    const f32x4 e0 = ntl4(ep);
    const f32x4 e1 = ntl4(ep + 256);
    const f32x4 e2 = ntl4(ep + 512);
    const f32x4 e3 = ntl4(ep + 768);
    const f32x4 f0 = ntl4(fp);
    const f32x4 f1 = ntl4(fp + 256);
    const f32x4 f2 = ntl4(fp + 512);
    const f32x4 f3 = ntl4(fp + 768);
    float p = hq0.x*e0.x + hq0.y*e0.y + hq0.z*e0.z + hq0.w*e0.w
            + hq1.x*e1.x + hq1.y*e1.y + hq1.z*e1.z + hq1.w*e1.w
            + hq2.x*e2.x + hq2.y*e2.y + hq2.z*e2.z + hq2.w*e2.w
            + hq3.x*e3.x + hq3.y*e3.y + hq3.z*e3.z + hq3.w*e3.w;
    float q = hq0.x*f0.x + hq0.y*f0.y + hq0.z*f0.z + hq0.w*f0.w
            + hq1.x*f1.x + hq1.y*f1.y + hq1.z*f1.z + hq1.w*f1.w
            + hq2.x*f2.x + hq2.y*f2.y + hq2.z*f2.z + hq2.w*f2.w
            + hq3.x*f3.x + hq3.y*f3.y + hq3.z*f3.z + hq3.w*f3.w;
    p += __shfl_xor(p, 1);  q += __shfl_xor(q, 1);
    p += __shfl_xor(p, 2);  q += __shfl_xor(q, 2);
    p += __shfl_xor(p, 4);  q += __shfl_xor(q, 4);
    p += __shfl_xor(p, 8);  q += __shfl_xor(q, 8);
    p += __shfl_xor(p, 16); q += __shfl_xor(q, 16);
    p += __shfl_xor(p, 32); q += __shfl_xor(q, 32);
    if (lane == 0) {
      float2 pq; pq.x = p; pq.y = q;
      *(float2*)(energ + (size_t)b*SS + sw + i) = pq;
    }
    const float mn = fmaxf(fmaxf(m, p), q);
    const float sc = __expf(m - mn);
    const float pe = __expf(p - mn);
    const float qe = __expf(q - mn);
    l = l*sc + pe + qe;
    cacc[0]  = cacc[0]*sc  + pe*e0.x + qe*f0.x;
    cacc[1]  = cacc[1]*sc  + pe*e0.y + qe*f0.y;
    cacc[2]  = cacc[2]*sc  + pe*e0.z + qe*f0.z;
    cacc[3]  = cacc[3]*sc  + pe*e0.w + qe*f0.w;
    cacc[4]  = cacc[4]*sc  + pe*e1.x + qe*f1.x;
    cacc[5]  = cacc[5]*sc  + pe*e1.y + qe*f1.y;
    cacc[6]  = cacc[6]*sc  + pe*e1.z + qe*f1.z;
    cacc[7]  = cacc[7]*sc  + pe*e1.w + qe*f1.w;
    cacc[8]  = cacc[8]*sc  + pe*e2.x + qe*f2.x;
    cacc[9]  = cacc[9]*sc  + pe*e2.y + qe*f2.y;
    cacc[10] = cacc[10]*sc + pe*e2.z + qe*f2.z;
    cacc[11] = cacc[11]*sc + pe*e2.w + qe*f2.w;
    cacc[12] = cacc[12]*sc + pe*e3.x + qe*f3.x;
    cacc[13] = cacc[13]*sc + pe*e3.y + qe*f3.y;
    cacc[14] = cacc[14]*sc + pe*e3.z + qe*f3.z;
    cacc[15] = cacc[15]*sc + pe*e3.w + qe*f3.w;
    m = mn;
  }

  // cross-wave combine; positions: j*256 + lane*4 + i (absolute layout)
  __shared__ float sm[4], sl[4];
  __shared__ float sctx[4][1024];
  if (lane == 0) { sm[wave] = m; sl[wave] = l; }
  __syncthreads();
  const float mg = fmaxf(fmaxf(sm[0], sm[1]), fmaxf(sm[2], sm[3]));
  const float lg = sl[0]*__expf(sm[0]-mg) + sl[1]*__expf(sm[1]-mg)
                 + sl[2]*__expf(sm[2]-mg) + sl[3]*__expf(sm[3]-mg);
  const float scw = __expf(m - mg);
  #pragma unroll
  for (int j = 0; j < 4; ++j) {
    float4 v;
    v.x = cacc[j*4+0]*scw; v.y = cacc[j*4+1]*scw;
    v.z = cacc[j*4+2]*scw; v.w = cacc[j*4+3]*scw;
    *(float4*)&sctx[wave][j*256 + lane*4] = v;
  }
  __syncthreads();
  const int d = threadIdx.x * 4;
  const float4 a0 = *(const float4*)&sctx[0][d];
  const float4 a1 = *(const float4*)&sctx[1][d];
  const float4 a2 = *(const float4*)&sctx[2][d];
  const float4 a3 = *(const float4*)&sctx[3][d];
  float4 rr;
  rr.x = a0.x+a1.x+a2.x+a3.x; rr.y = a0.y+a1.y+a2.y+a3.y;
  rr.z = a0.z+a1.z+a2.z+a3.z; rr.w = a0.w+a1.w+a2.w+a3.w;
  *(float4*)(ctxpart + ((size_t)(b*C + ch))*HH + d) = rr;
  if (threadIdx.x == 0) { mpart[b*C+ch] = mg; lpart[b*C+ch] = lg; }
}

// ---------------- attention combine + ctx bf16 into concA[:,1024:2048] --------
__global__ void k_attn_fin(const float* __restrict__ mpart, const float* __restrict__ lpart,
                           const float* __restrict__ ctxpart, const float* __restrict__ energ,
                           float* __restrict__ attn, short* __restrict__ concA, int C){
  const int b = blockIdx.x, tid = threadIdx.x;
  float m = -INFINITY;
  for (int c = 0; c < C; ++c) m = fmaxf(m, mpart[b*C+c]);
  float l = 0.f;
  for (int c = 0; c < C; ++c) l += lpart[b*C+c] * __expf(mpart[b*C+c] - m);
  const float inv = 1.0f / l;
  float ax = 0.f, ay = 0.f, az = 0.f, aw = 0.f;
  for (int c = 0; c < C; ++c) {
    const float w = __expf(mpart[b*C+c] - m);
    const float* cp = ctxpart + ((size_t)(b*C+c))*HH + tid*4;
    ax += w*cp[0]; ay += w*cp[1]; az += w*cp[2]; aw += w*cp[3];
  }
  ax *= inv; ay *= inv; az *= inv; aw *= inv;
  short* ca = concA + (size_t)b*2048 + 1024 + tid*4;
  ca[0] = f2bf(ax); ca[1] = f2bf(ay); ca[2] = f2bf(az); ca[3] = f2bf(aw);
  for (int j = 0; j < 8; ++j) {
    const int s = j*256 + tid;
    attn[(size_t)b*SS + s] = __expf(energ[(size_t)b*SS + s] - m) * inv;
  }
}

extern "C" void kernel_launch(void* const* d_in, const int* in_sizes, int n_in,
                              void* d_out, int out_size, void* d_ws, size_t ws_size,
                              hipStream_t stream){
  const int*   seq  = (const int*)  d_in[0];
  const float* h0   = (const float*)d_in[1];
  const float* c0   = (const float*)d_in[2];
  const float* enc  = (const float*)d_in[3];
  const float* embW = (const float*)d_in[4];
  const float* W_ih = (const float*)d_in[5];
  const float* W_hh = (const float*)d_in[6];
  const float* b_ih = (const float*)d_in[7];
  const float* b_hh = (const float*)d_in[8];
  const float* cW   = (const float*)d_in[9];
  const float* cb   = (const float*)d_in[10];
  const float* oW   = (const float*)d_in[11];
  const float* ob   = (const float*)d_in[12];
  float* out = (float*)d_out;

  float* ws = (float*)d_ws;
  // ws layout (float offsets)
  const size_t o_energ = 0;            // 131072
  const size_t o_concA = 131072;       // 65536  (64x2048 bf16)
  const size_t o_concB = 196608;       // 32768  (64x1024 bf16)
  const size_t o_Ahi   = 229376;       // 65536  (64x2048 bf16)
  const size_t o_Alo   = 294912;       // 65536
  const size_t o_mp    = 360448;
  const size_t SKPART  = 4194304;      // 16*64*4096 fp32 partials
  int C = 32;
  for (;;) {
    size_t need = (o_mp + (size_t)64*C*2 + (size_t)64*C*1024 + SKPART) * sizeof(float);
    if (need <= ws_size || C == 1) break;
    C >>= 1;
  }
  float* energ   = ws + o_energ;
  short* concA   = (short*)(ws + o_concA);
  short* concB   = (short*)(ws + o_concB);
  short* Ahi     = (short*)(ws + o_Ahi);
  short* Alo     = (short*)(ws + o_Alo);
  float* mpart   = ws + o_mp;
  float* lpart   = mpart + (size_t)64*C;
  float* ctxpart = lpart + (size_t)64*C;
  float* skpart  = ctxpart + (size_t)64*C*1024;

  const size_t o_h = 3216448, o_c = 3281984, o_attn = 3347520;

  // A = [emb[seq] | h0] as bf16 hi/lo pair
  k_prep<<<64, 256, 0, stream>>>(seq, embW, h0, Ahi, Alo);
  // gates partials via pair-MFMA (split-K 16)
  k_gates<<<dim3(32,16), 256, 0, stream>>>(Ahi, Alo, W_ih, W_hh, skpart);
  // reduce + biases + LSTM pointwise -> h, c, concA[:, :1024] (bf16)
  k_rlstm<<<256, 256, 0, stream>>>(skpart, b_ih, b_hh, c0, out + o_h, out + o_c,
                                   concA, 16);
  // fused attention (single encoder read; non-temporal streaming)
  k_attn_part<<<64*C, 256, 0, stream>>>(out + o_h, enc, energ, mpart, lpart, ctxpart, C);
  k_attn_fin<<<64, 256, 0, stream>>>(mpart, lpart, ctxpart, energ, out + o_attn, concA, C);
  // concat_out = tanh([h,ctx] @ cW^T + cb) -> bf16 (MFMA, split-K 16)
  k_mfma<<<dim3(8,16), 256, 0, stream>>>(concA, 2048, cW, 2048, skpart, 1024, 2048);
  k_reduce<<<256, 256, 0, stream>>>(skpart, cb, concB, 1024, 16);
  // logits = concat_out @ out_W^T + out_b  (4-way K-split, non-temporal W)
  k_logits4<<<1571, 256, 0, stream>>>(concB, oW, ob, out);
}

// Round 13
// 240.379 us; speedup vs baseline: 1.2265x; 1.0524x over previous
//
#include <hip/hip_runtime.h>
#include <hip/hip_bf16.h>
#include <math.h>

#define BB 64
#define HH 1024
#define SS 2048
#define VV 50257

typedef float f32x4 __attribute__((ext_vector_type(4)));
typedef short bf16x8 __attribute__((ext_vector_type(8)));

__device__ __forceinline__ float sigf(float x){ return 1.0f/(1.0f+__expf(-x)); }
__device__ __forceinline__ short f2bf(float f){
  __hip_bfloat16 h = __float2bfloat16(f);
  return __builtin_bit_cast(short, h);
}
__device__ __forceinline__ float bf2f(short s){
  __hip_bfloat16 h = __builtin_bit_cast(__hip_bfloat16, s);
  return __bfloat162float(h);
}
// non-temporal 16B load: ONLY for enc (536 MB, can never be L3-resident).
// oW (206 MB) stays CACHEABLE so it remains L3-resident across graph replays.
__device__ __forceinline__ f32x4 ntl4(const float* p){
  return __builtin_nontemporal_load((const f32x4*)p);
}

// ------ prep: A = [emb[seq] | h0] split into bf16 hi/lo pair  [64][2048] -----
__global__ void k_prep(const int* __restrict__ seq, const float* __restrict__ embW,
                       const float* __restrict__ h0,
                       short* __restrict__ Ahi, short* __restrict__ Alo){
  const int b = blockIdx.x;
  const int k = threadIdx.x * 8;     // 0..2047
  const float* src = (k < 1024) ? (embW + (size_t)seq[b]*1024 + k)
                                : (h0 + (size_t)b*1024 + (k - 1024));
  float4 v0 = *(const float4*)src;
  float4 v1 = *(const float4*)(src + 4);
  float v[8] = {v0.x,v0.y,v0.z,v0.w,v1.x,v1.y,v1.z,v1.w};
  bf16x8 hi, lo;
  #pragma unroll
  for (int j = 0; j < 8; ++j) {
    short h = f2bf(v[j]);
    hi[j] = h;
    lo[j] = f2bf(v[j] - bf2f(h));
  }
  *(bf16x8*)(Ahi + (size_t)b*2048 + k) = hi;
  *(bf16x8*)(Alo + (size_t)b*2048 + k) = lo;
}

// ------ gates GEMM via bf16-pair MFMA: partials dst[sk][64][4096] ------------
__global__ __launch_bounds__(256, 3)
void k_gates(const short* __restrict__ Ahi, const short* __restrict__ Alo,
             const float* __restrict__ W_ih, const float* __restrict__ W_hh,
             float* __restrict__ dst)
{
  const int tid = threadIdx.x;
  const int wave = tid >> 6, lane = tid & 63;
  const int r = lane & 15, g = lane >> 4;
  const int nb = blockIdx.x, sk = blockIdx.y;
  const int n0 = nb*128 + wave*32;
  const int kbase = sk*128;
  const float* Wm = (kbase < 1024) ? W_ih : W_hh;
  const int kw = (kbase < 1024) ? kbase : (kbase - 1024);

  f32x4 acc[4][2] = {};

  #pragma unroll
  for (int ks = 0; ks < 4; ++ks) {
    const int kk = kbase + ks*32 + g*8;     // A offset
    const int ko = kw   + ks*32 + g*8;      // W offset
    bf16x8 ahi[4], alo[4];
    #pragma unroll
    for (int mf = 0; mf < 4; ++mf) {
      ahi[mf] = *(const bf16x8*)(Ahi + (size_t)(mf*16 + r)*2048 + kk);
      alo[mf] = *(const bf16x8*)(Alo + (size_t)(mf*16 + r)*2048 + kk);
    }
    #pragma unroll
    for (int nf = 0; nf < 2; ++nf) {
      const int n = n0 + nf*16 + r;
      const float* wp = Wm + (size_t)n*1024 + ko;
      float4 w0 = *(const float4*)wp;
      float4 w1 = *(const float4*)(wp + 4);
      float wv[8] = {w0.x,w0.y,w0.z,w0.w,w1.x,w1.y,w1.z,w1.w};
      bf16x8 whi, wlo;
      #pragma unroll
      for (int j = 0; j < 8; ++j) {
        short h = f2bf(wv[j]);
        whi[j] = h;
        wlo[j] = f2bf(wv[j] - bf2f(h));
      }
      #pragma unroll
      for (int mf = 0; mf < 4; ++mf) {
        acc[mf][nf] = __builtin_amdgcn_mfma_f32_16x16x32_bf16(ahi[mf], whi, acc[mf][nf], 0,0,0);
        acc[mf][nf] = __builtin_amdgcn_mfma_f32_16x16x32_bf16(alo[mf], whi, acc[mf][nf], 0,0,0);
        acc[mf][nf] = __builtin_amdgcn_mfma_f32_16x16x32_bf16(ahi[mf], wlo, acc[mf][nf], 0,0,0);
      }
    }
  }

  #pragma unroll
  for (int nf = 0; nf < 2; ++nf) {
    const int n = n0 + nf*16 + r;
    #pragma unroll
    for (int mf = 0; mf < 4; ++mf)
      #pragma unroll
      for (int j = 0; j < 4; ++j)
        dst[((size_t)sk*64 + (mf*16 + g*4 + j))*4096 + n] = acc[mf][nf][j];
  }
}

// -------- fused split-K reduce + bias + LSTM pointwise -> h, c, concA[:, :1024]
__global__ void k_rlstm(const float* __restrict__ part, const float* __restrict__ b_ih,
                        const float* __restrict__ b_hh, const float* __restrict__ c0,
                        float* __restrict__ h_out, float* __restrict__ c_out,
                        short* __restrict__ concA, int SK){
  int idx = blockIdx.x*256 + threadIdx.x;    // 64*1024
  int b = idx >> 10, k = idx & 1023;
  float gi = b_ih[k]      + b_hh[k];
  float gf = b_ih[1024+k] + b_hh[1024+k];
  float gg = b_ih[2048+k] + b_hh[2048+k];
  float go = b_ih[3072+k] + b_hh[3072+k];
  const float* p = part + (size_t)b*4096 + k;
  for (int s = 0; s < SK; ++s) {
    const float* ps = p + (size_t)s*64*4096;
    gi += ps[0]; gf += ps[1024]; gg += ps[2048]; go += ps[3072];
  }
  float c = sigf(gf)*c0[idx] + sigf(gi)*tanhf(gg);
  float h = sigf(go)*tanhf(c);
  c_out[idx] = c;
  h_out[idx] = h;
  concA[(size_t)b*2048 + k] = f2bf(h);
}

// ---------------- streaming bf16 MFMA GEMM (concat): partials dst[sk][64][N] --
__global__ __launch_bounds__(256)
void k_mfma(const short* __restrict__ A, int lda,
            const float* __restrict__ W1, int ldw,
            float* __restrict__ dst, int N, int Ktot)
{
  const int tid  = threadIdx.x;
  const int wave = tid >> 6, lane = tid & 63;
  const int nb = blockIdx.x, sk = blockIdx.y, SK = gridDim.y;
  const int ksteps = Ktot >> 5;
  const int kps = ksteps / SK;
  const int k0 = sk * kps;
  const int n0 = nb*128 + wave*32;
  const int r = lane & 15, g = lane >> 4;

  f32x4 acc[4][2] = {};

  for (int ks = k0; ks < k0 + kps; ++ks) {
    const int kk = (ks << 5) + g*8;
    bf16x8 af[4];
    #pragma unroll
    for (int mf = 0; mf < 4; ++mf)
      af[mf] = *(const bf16x8*)(A + (size_t)(mf*16 + r)*lda + kk);
    #pragma unroll
    for (int nf = 0; nf < 2; ++nf) {
      const int n = n0 + nf*16 + r;
      const float* wp = W1 + (size_t)n*ldw + kk;
      float4 w0 = *(const float4*)wp;
      float4 w1 = *(const float4*)(wp + 4);
      bf16x8 bfr;
      bfr[0]=f2bf(w0.x); bfr[1]=f2bf(w0.y); bfr[2]=f2bf(w0.z); bfr[3]=f2bf(w0.w);
      bfr[4]=f2bf(w1.x); bfr[5]=f2bf(w1.y); bfr[6]=f2bf(w1.z); bfr[7]=f2bf(w1.w);
      #pragma unroll
      for (int mf = 0; mf < 4; ++mf)
        acc[mf][nf] = __builtin_amdgcn_mfma_f32_16x16x32_bf16(af[mf], bfr, acc[mf][nf], 0, 0, 0);
    }
  }

  #pragma unroll
  for (int nf = 0; nf < 2; ++nf) {
    const int n = n0 + nf*16 + r;
    #pragma unroll
    for (int mf = 0; mf < 4; ++mf)
      #pragma unroll
      for (int j = 0; j < 4; ++j)
        dst[((size_t)sk*64 + (mf*16 + g*4 + j))*N + n] = acc[mf][nf][j];
  }
}

// ---------------- split-K reduce + bias + tanh -> bf16 ------------------------
__global__ void k_reduce(const float* __restrict__ part, const float* __restrict__ bias,
                         short* __restrict__ dstb, int N, int SK){
  size_t idx = (size_t)blockIdx.x*256 + threadIdx.x;
  if (idx >= (size_t)64*N) return;
  int b = (int)(idx / N), n = (int)(idx % N);
  float v = bias[n];
  for (int s = 0; s < SK; ++s) v += part[((size_t)s*64 + b)*N + n];
  dstb[(size_t)b*N + n] = f2bf(tanhf(v));
}

// ------ logits: D[64][50257] = A_bf16[64][1024] @ oW^T + ob -------------------
// Direct-streaming MFMA, 4-way in-block K-split. W loads CACHEABLE: oW (206 MB)
// fits the 256 MB L3 and stays resident across graph replays since enc (the
// only larger stream) is non-temporal and never evicts it.
__global__ __launch_bounds__(256)
void k_logits4(const short* __restrict__ A, const float* __restrict__ W,
               const float* __restrict__ bias, float* __restrict__ out)
{
  __shared__ float red[4][32][64];   // 32 KB
  const int tid = threadIdx.x;
  const int wave = tid >> 6, lane = tid & 63;
  const int r = lane & 15, g = lane >> 4;
  const int n0 = blockIdx.x * 32;
  const int nA = n0 + r, nB = n0 + 16 + r;
  const int nAc = (nA < VV) ? nA : (VV - 1);
  const int nBc = (nB < VV) ? nB : (VV - 1);
  const int kb = wave * 256;

  const short* A0 = A + (size_t)r*1024 + kb + g*8;
  const float* wA = W + (size_t)nAc*1024 + kb + g*8;
  const float* wB = W + (size_t)nBc*1024 + kb + g*8;

  f32x4 acc[4][2] = {};

  #pragma unroll
  for (int ks = 0; ks < 8; ++ks) {
    const int o = ks*32;
    const float4 u0 = *(const float4*)(wA + o);
    const float4 u1 = *(const float4*)(wA + o + 4);
    const float4 v0 = *(const float4*)(wB + o);
    const float4 v1 = *(const float4*)(wB + o + 4);
    bf16x8 bA, bB;
    bA[0]=f2bf(u0.x); bA[1]=f2bf(u0.y); bA[2]=f2bf(u0.z); bA[3]=f2bf(u0.w);
    bA[4]=f2bf(u1.x); bA[5]=f2bf(u1.y); bA[6]=f2bf(u1.z); bA[7]=f2bf(u1.w);
    bB[0]=f2bf(v0.x); bB[1]=f2bf(v0.y); bB[2]=f2bf(v0.z); bB[3]=f2bf(v0.w);
    bB[4]=f2bf(v1.x); bB[5]=f2bf(v1.y); bB[6]=f2bf(v1.z); bB[7]=f2bf(v1.w);
    #pragma unroll
    for (int mf = 0; mf < 4; ++mf) {
      const bf16x8 af = *(const bf16x8*)(A0 + (size_t)mf*16*1024 + o);
      acc[mf][0] = __builtin_amdgcn_mfma_f32_16x16x32_bf16(af, bA, acc[mf][0], 0,0,0);
      acc[mf][1] = __builtin_amdgcn_mfma_f32_16x16x32_bf16(af, bB, acc[mf][1], 0,0,0);
    }
  }

  // deposit all 4 waves' partials
  #pragma unroll
  for (int nf = 0; nf < 2; ++nf)
    #pragma unroll
    for (int mf = 0; mf < 4; ++mf)
      #pragma unroll
      for (int j = 0; j < 4; ++j)
        red[wave][nf*16 + mf*4 + j][lane] = acc[mf][nf][j];
  __syncthreads();

  // each wave reduces 8 of the 32 (row,colgroup) values and writes
  #pragma unroll
  for (int vi = 0; vi < 8; ++vi) {
    const int v  = wave*8 + vi;
    const int nf = v >> 4, mf = (v >> 2) & 3, j = v & 3;
    const float s = red[0][v][lane] + red[1][v][lane]
                  + red[2][v][lane] + red[3][v][lane];
    const int col = n0 + nf*16 + r;
    if (col < VV)
      out[(size_t)(mf*16 + g*4 + j)*VV + col] = s + bias[col];
  }
}

// ---------------- attention pass 1: quarter-mapped lanes, NT enc loads --------
// Lane l owns elements {j*256 + l*4 + i}; each enc load instruction is 1 KB
// contiguous AND non-temporal (enc can never be cache-resident; keep L3 for oW).
__global__ __launch_bounds__(256)
void k_attn_part(const float* __restrict__ h, const float* __restrict__ enc,
                 float* __restrict__ energ, float* __restrict__ mpart,
                 float* __restrict__ lpart, float* __restrict__ ctxpart, int C){
  const int b  = blockIdx.x & 63;
  const int ch = blockIdx.x >> 6;
  const int wave = threadIdx.x >> 6;
  const int lane = threadIdx.x & 63;
  const int rows = SS / C;
  const int rpw  = rows >> 2;
  const int sw = ch*rows + wave*rpw;

  f32x4 hq0, hq1, hq2, hq3;
  {
    const float* hb = h + (size_t)b*HH + lane*4;
    hq0 = *(const f32x4*)(hb);
    hq1 = *(const f32x4*)(hb + 256);
    hq2 = *(const f32x4*)(hb + 512);
    hq3 = *(const f32x4*)(hb + 768);
  }
  float m = -INFINITY, l = 0.f;
  float cacc[16];
  #pragma unroll
  for (int j = 0; j < 16; ++j) cacc[j] = 0.f;

  for (int i = 0; i < rpw; i += 2) {
    const float* ep = enc + ((size_t)(sw+i)*BB + b)*HH + lane*4;
    const float* fp = ep + (size_t)BB*HH;
    const f32x4 e0 = ntl4(ep);
    const f32x4 e1 = ntl4(ep + 256);
    const f32x4 e2 = ntl4(ep + 512);
    const f32x4 e3 = ntl4(ep + 768);
    const f32x4 f0 = ntl4(fp);
    const f32x4 f1 = ntl4(fp + 256);
    const f32x4 f2 = ntl4(fp + 512);
    const f32x4 f3 = ntl4(fp + 768);
    float p = hq0.x*e0.x + hq0.y*e0.y + hq0.z*e0.z + hq0.w*e0.w
            + hq1.x*e1.x + hq1.y*e1.y + hq1.z*e1.z + hq1.w*e1.w
            + hq2.x*e2.x + hq2.y*e2.y + hq2.z*e2.z + hq2.w*e2.w
            + hq3.x*e3.x + hq3.y*e3.y + hq3.z*e3.z + hq3.w*e3.w;
    float q = hq0.x*f0.x + hq0.y*f0.y + hq0.z*f0.z + hq0.w*f0.w
            + hq1.x*f1.x + hq1.y*f1.y + hq1.z*f1.z + hq1.w*f1.w
            + hq2.x*f2.x + hq2.y*f2.y + hq2.z*f2.z + hq2.w*f2.w
            + hq3.x*f3.x + hq3.y*f3.y + hq3.z*f3.z + hq3.w*f3.w;
    p += __shfl_xor(p, 1);  q += __shfl_xor(q, 1);
    p += __shfl_xor(p, 2);  q += __shfl_xor(q, 2);
    p += __shfl_xor(p, 4);  q += __shfl_xor(q, 4);
    p += __shfl_xor(p, 8);  q += __shfl_xor(q, 8);
    p += __shfl_xor(p, 16); q += __shfl_xor(q, 16);
    p += __shfl_xor(p, 32); q += __shfl_xor(q, 32);
    if (lane == 0) {
      float2 pq; pq.x = p; pq.y = q;
      *(float2*)(energ + (size_t)b*SS + sw + i) = pq;
    }
    const float mn = fmaxf(fmaxf(m, p), q);
    const float sc = __expf(m - mn);
    const float pe = __expf(p - mn);
    const float qe = __expf(q - mn);
    l = l*sc + pe + qe;
    cacc[0]  = cacc[0]*sc  + pe*e0.x + qe*f0.x;
    cacc[1]  = cacc[1]*sc  + pe*e0.y + qe*f0.y;
    cacc[2]  = cacc[2]*sc  + pe*e0.z + qe*f0.z;
    cacc[3]  = cacc[3]*sc  + pe*e0.w + qe*f0.w;
    cacc[4]  = cacc[4]*sc  + pe*e1.x + qe*f1.x;
    cacc[5]  = cacc[5]*sc  + pe*e1.y + qe*f1.y;
    cacc[6]  = cacc[6]*sc  + pe*e1.z + qe*f1.z;
    cacc[7]  = cacc[7]*sc  + pe*e1.w + qe*f1.w;
    cacc[8]  = cacc[8]*sc  + pe*e2.x + qe*f2.x;
    cacc[9]  = cacc[9]*sc  + pe*e2.y + qe*f2.y;
    cacc[10] = cacc[10]*sc + pe*e2.z + qe*f2.z;
    cacc[11] = cacc[11]*sc + pe*e2.w + qe*f2.w;
    cacc[12] = cacc[12]*sc + pe*e3.x + qe*f3.x;
    cacc[13] = cacc[13]*sc + pe*e3.y + qe*f3.y;
    cacc[14] = cacc[14]*sc + pe*e3.z + qe*f3.z;
    cacc[15] = cacc[15]*sc + pe*e3.w + qe*f3.w;
    m = mn;
  }

  // cross-wave combine; positions: j*256 + lane*4 + i (absolute layout)
  __shared__ float sm[4], sl[4];
  __shared__ float sctx[4][1024];
  if (lane == 0) { sm[wave] = m; sl[wave] = l; }
  __syncthreads();
  const float mg = fmaxf(fmaxf(sm[0], sm[1]), fmaxf(sm[2], sm[3]));
  const float lg = sl[0]*__expf(sm[0]-mg) + sl[1]*__expf(sm[1]-mg)
                 + sl[2]*__expf(sm[2]-mg) + sl[3]*__expf(sm[3]-mg);
  const float scw = __expf(m - mg);
  #pragma unroll
  for (int j = 0; j < 4; ++j) {
    float4 v;
    v.x = cacc[j*4+0]*scw; v.y = cacc[j*4+1]*scw;
    v.z = cacc[j*4+2]*scw; v.w = cacc[j*4+3]*scw;
    *(float4*)&sctx[wave][j*256 + lane*4] = v;
  }
  __syncthreads();
  const int d = threadIdx.x * 4;
  const float4 a0 = *(const float4*)&sctx[0][d];
  const float4 a1 = *(const float4*)&sctx[1][d];
  const float4 a2 = *(const float4*)&sctx[2][d];
  const float4 a3 = *(const float4*)&sctx[3][d];
  float4 rr;
  rr.x = a0.x+a1.x+a2.x+a3.x; rr.y = a0.y+a1.y+a2.y+a3.y;
  rr.z = a0.z+a1.z+a2.z+a3.z; rr.w = a0.w+a1.w+a2.w+a3.w;
  *(float4*)(ctxpart + ((size_t)(b*C + ch))*HH + d) = rr;
  if (threadIdx.x == 0) { mpart[b*C+ch] = mg; lpart[b*C+ch] = lg; }
}

// ---------------- attention combine + ctx bf16 into concA[:,1024:2048] --------
__global__ void k_attn_fin(const float* __restrict__ mpart, const float* __restrict__ lpart,
                           const float* __restrict__ ctxpart, const float* __restrict__ energ,
                           float* __restrict__ attn, short* __restrict__ concA, int C){
  const int b = blockIdx.x, tid = threadIdx.x;
  float m = -INFINITY;
  for (int c = 0; c < C; ++c) m = fmaxf(m, mpart[b*C+c]);
  float l = 0.f;
  for (int c = 0; c < C; ++c) l += lpart[b*C+c] * __expf(mpart[b*C+c] - m);
  const float inv = 1.0f / l;
  float ax = 0.f, ay = 0.f, az = 0.f, aw = 0.f;
  for (int c = 0; c < C; ++c) {
    const float w = __expf(mpart[b*C+c] - m);
    const float* cp = ctxpart + ((size_t)(b*C+c))*HH + tid*4;
    ax += w*cp[0]; ay += w*cp[1]; az += w*cp[2]; aw += w*cp[3];
  }
  ax *= inv; ay *= inv; az *= inv; aw *= inv;
  short* ca = concA + (size_t)b*2048 + 1024 + tid*4;
  ca[0] = f2bf(ax); ca[1] = f2bf(ay); ca[2] = f2bf(az); ca[3] = f2bf(aw);
  for (int j = 0; j < 8; ++j) {
    const int s = j*256 + tid;
    attn[(size_t)b*SS + s] = __expf(energ[(size_t)b*SS + s] - m) * inv;
  }
}

extern "C" void kernel_launch(void* const* d_in, const int* in_sizes, int n_in,
                              void* d_out, int out_size, void* d_ws, size_t ws_size,
                              hipStream_t stream){
  const int*   seq  = (const int*)  d_in[0];
  const float* h0   = (const float*)d_in[1];
  const float* c0   = (const float*)d_in[2];
  const float* enc  = (const float*)d_in[3];
  const float* embW = (const float*)d_in[4];
  const float* W_ih = (const float*)d_in[5];
  const float* W_hh = (const float*)d_in[6];
  const float* b_ih = (const float*)d_in[7];
  const float* b_hh = (const float*)d_in[8];
  const float* cW   = (const float*)d_in[9];
  const float* cb   = (const float*)d_in[10];
  const float* oW   = (const float*)d_in[11];
  const float* ob   = (const float*)d_in[12];
  float* out = (float*)d_out;

  float* ws = (float*)d_ws;
  // ws layout (float offsets)
  const size_t o_energ = 0;            // 131072
  const size_t o_concA = 131072;       // 65536  (64x2048 bf16)
  const size_t o_concB = 196608;       // 32768  (64x1024 bf16)
  const size_t o_Ahi   = 229376;       // 65536  (64x2048 bf16)
  const size_t o_Alo   = 294912;       // 65536
  const size_t o_mp    = 360448;
  const size_t SKPART  = 4194304;      // 16*64*4096 fp32 partials
  int C = 32;
  for (;;) {
    size_t need = (o_mp + (size_t)64*C*2 + (size_t)64*C*1024 + SKPART) * sizeof(float);
    if (need <= ws_size || C == 1) break;
    C >>= 1;
  }
  float* energ   = ws + o_energ;
  short* concA   = (short*)(ws + o_concA);
  short* concB   = (short*)(ws + o_concB);
  short* Ahi     = (short*)(ws + o_Ahi);
  short* Alo     = (short*)(ws + o_Alo);
  float* mpart   = ws + o_mp;
  float* lpart   = mpart + (size_t)64*C;
  float* ctxpart = lpart + (size_t)64*C;
  float* skpart  = ctxpart + (size_t)64*C*1024;

  const size_t o_h = 3216448, o_c = 3281984, o_attn = 3347520;

  // A = [emb[seq] | h0] as bf16 hi/lo pair
  k_prep<<<64, 256, 0, stream>>>(seq, embW, h0, Ahi, Alo);
  // gates partials via pair-MFMA (split-K 16)
  k_gates<<<dim3(32,16), 256, 0, stream>>>(Ahi, Alo, W_ih, W_hh, skpart);
  // reduce + biases + LSTM pointwise -> h, c, concA[:, :1024] (bf16)
  k_rlstm<<<256, 256, 0, stream>>>(skpart, b_ih, b_hh, c0, out + o_h, out + o_c,
                                   concA, 16);
  // fused attention (single encoder read; non-temporal streaming)
  k_attn_part<<<64*C, 256, 0, stream>>>(out + o_h, enc, energ, mpart, lpart, ctxpart, C);
  k_attn_fin<<<64, 256, 0, stream>>>(mpart, lpart, ctxpart, energ, out + o_attn, concA, C);
  // concat_out = tanh([h,ctx] @ cW^T + cb) -> bf16 (MFMA, split-K 16)
  k_mfma<<<dim3(8,16), 256, 0, stream>>>(concA, 2048, cW, 2048, skpart, 1024, 2048);
  k_reduce<<<256, 256, 0, stream>>>(skpart, cb, concB, 1024, 16);
  // logits = concat_out @ out_W^T + out_b  (4-way K-split, CACHEABLE W -> L3-resident)
  k_logits4<<<1571, 256, 0, stream>>>(concB, oW, ob, out);
}